// Round 12
// baseline (649.146 us; speedup 1.0000x reference)
//
#include <hip/hip_runtime.h>
#include <math.h>

// ---------------------------------------------------------------------------
// Round 15: 4-waves/SIMD restructure (r7 geometry x champion mechanisms).
// r14 stagger was a flawed test: CU-mates are ~256 apart in blockIdx (even
// spacing) -> parity sleep hit both or neither; nothing de-phased. Instead of
// discriminating SIMD-mates, give the scheduler material: 512 thr, 8 waves,
// wave = 64out x 64pt (acc[2][2]=64), 80KB single-buffer LDS -> 2 blocks/CU
// -> 16 waves/CU = 4/SIMD. When one wave loads, three others MFMA ->
// instruction-granular de-phasing. r7's 711us had 1 block/CU (no slip), no
// pins, 144KB dbuf; all fixed here. launch_bounds(512,4) caps regs at ~192
// (est ~154 incl acc; r4 proved 4/SIMD at 184). A-frags served to wc-pairs
// via L1; LDS traffic per CU unchanged. K-loop = champion pinned depth-1
// even/odd ping-pong (sched_barrier pins + setprio). Success gate:
// OccupancyPercent ~40+.
// Numerics unchanged: bf16 W+act, fp32 acc (absmax ~3.9e-3 vs thr 1.148e-2).
// ---------------------------------------------------------------------------

typedef __attribute__((ext_vector_type(8))) short short8;
typedef __attribute__((ext_vector_type(4))) float f32x4;
typedef __attribute__((ext_vector_type(16))) float f32x16;

struct WPtrs { const float* w[8]; };
struct BPtrs { const float* b[8]; };

#define INV2PI 0.15915494309189533577f

// kk-block (K=16) offsets in elems (kkg * 4096):
// L0: 4kk @0, L1-L4: 16kk @4/20/36/52, L5: 20kk @68, L6: 16kk @88, L7 @104.
#define PK_L0 0
#define PK_L1 16384
#define PK_L2 81920
#define PK_L3 147456
#define PK_L4 212992
#define PK_L5 278528
#define PK_L6 360448
#define PK_L7 425984
#define PK_W8 491520           // [j=0..15][k=0..255]
#define PK_TOTAL 495616

__device__ __forceinline__ unsigned short f2bf(float v) {
  unsigned u = __float_as_uint(v);
  u = u + 0x7fffu + ((u >> 16) & 1u);
  return (unsigned short)(u >> 16);
}
__device__ __forceinline__ float bf_lo(unsigned u) { return __uint_as_float(u << 16); }
__device__ __forceinline__ float bf_hi(unsigned u) { return __uint_as_float(u & 0xffff0000u); }

__device__ __forceinline__ unsigned cvtpk(float a, float b) {
#if __has_builtin(__builtin_amdgcn_cvt_pk_bf16_f32)
  typedef __attribute__((ext_vector_type(2))) __bf16 bf16x2_t;
  bf16x2_t r = __builtin_amdgcn_cvt_pk_bf16_f32(a, b);
  return __builtin_bit_cast(unsigned, r);
#else
  unsigned ua = __float_as_uint(a);
  ua += 0x7fffu + ((ua >> 16) & 1u);
  unsigned ub = __float_as_uint(b);
  ub += 0x7fffu + ((ub >> 16) & 1u);
#if __has_builtin(__builtin_amdgcn_perm)
  return __builtin_amdgcn_perm(ub, ua, 0x07060302u);
#else
  return (ua >> 16) | (ub & 0xffff0000u);
#endif
#endif
}

__device__ __forceinline__ float fractf_(float x) {
#if __has_builtin(__builtin_amdgcn_fract_f32)
  return __builtin_amdgcn_fract_f32(x);
#else
  return x - floorf(x);
#endif
}
__device__ __forceinline__ float sin_rev(float rev) {
#if __has_builtin(__builtin_amdgcn_sinf)
  return __builtin_amdgcn_sinf(rev);
#else
  return __sinf(rev * 6.283185307179586f);
#endif
}

__device__ __forceinline__ float embval(int f, float c0, float c1, float c2,
                                        float x0, float x1, float x2) {
  if (f >= 63) return 0.0f;
  int d = (f >= 21 ? 1 : 0) + (f >= 42 ? 1 : 0);
  int r = f - d * 21;
  float c = (d == 0) ? c0 : (d == 1 ? c1 : c2);
  float x = (d == 0) ? x0 : (d == 1 ? x1 : x2);
  bool isc = r > 10;
  int e = isc ? (r - 11) : (r - 1);
  float rev = fractf_(ldexpf(x, e) + (isc ? 0.25f : 0.0f));
  float s = sin_rev(rev);
  return (r == 0) ? c : s;
}

__device__ __forceinline__ f32x16 mfma32(short8 a, short8 b, f32x16 c) {
  return __builtin_amdgcn_mfma_f32_32x32x16_bf16(a, b, c, 0, 0, 0);
}
__device__ __forceinline__ f32x4 mfma16(short8 a, short8 b, f32x4 c) {
  return __builtin_amdgcn_mfma_f32_16x16x32_bf16(a, b, c, 0, 0, 0);
}

// ---------------------------------------------------------------------------
// Prologue: pack weights as [kk][ch 0..255][16] bf16 (+ W8 as [j16][k256]).
// ---------------------------------------------------------------------------
__global__ void pack_weights(WPtrs W, const float* __restrict__ w8,
                             unsigned short* __restrict__ out) {
  int idx = blockIdx.x * 256 + threadIdx.x;
  if (idx >= PK_TOTAL) return;
  float v;
  if (idx >= PK_W8) {
    int t = idx - PK_W8;
    int j = t >> 8, k = t & 255;
    v = (j < 4) ? w8[k * 4 + j] : 0.0f;
  } else {
    int e = idx & 15;
    int blk = idx >> 4;
    int ch = blk & 255;
    int kkg = blk >> 8;              // 0..119
    int l, kk0;
    if      (kkg < 4)   { l = 0; kk0 = 0;   }
    else if (kkg < 20)  { l = 1; kk0 = 4;   }
    else if (kkg < 36)  { l = 2; kk0 = 20;  }
    else if (kkg < 52)  { l = 3; kk0 = 36;  }
    else if (kkg < 68)  { l = 4; kk0 = 52;  }
    else if (kkg < 88)  { l = 5; kk0 = 68;  }
    else if (kkg < 104) { l = 6; kk0 = 88;  }
    else                { l = 7; kk0 = 104; }
    int k = (kkg - kk0) * 16 + e;
    const int realK[8] = {63, 256, 256, 256, 256, 319, 256, 256};
    v = (k < realK[l]) ? W.w[l][k * 256 + ch] : 0.0f;
  }
  out[idx] = f2bf(v);
}

// ---------------------------------------------------------------------------
// One layer via 32x32x16, 128 points, 8 waves. Wave (wr,wc): out-ch
// [64wr,64wr+64) x pts [64wc,64wc+64). acc[2][2]. Champion pinned depth-1
// even/odd ping-pong: loads(kk+1) -> sched_barrier(0) -> setprio(1)
// MFMA4(kk) setprio(0) -> pin. srcA rows PAB bytes (XOR-swizzled 16B
// granules), KKB extra kk-blocks from emb (128B rows). RB: barrier before
// writeback (src aliases dst).
// ---------------------------------------------------------------------------
template <int KKA, int PAB, int KKB, bool RB>
__device__ __forceinline__ void do_layer32(
    const unsigned short* srcA, const unsigned short* srcB,
    const unsigned short* __restrict__ wblk,
    const float* __restrict__ bias,
    unsigned short* dst, int wr, int wc, int n, int h, unsigned swz) {
  f32x16 acc[2][2];
#pragma unroll
  for (int mt = 0; mt < 2; ++mt)
#pragma unroll
    for (int q = 0; q < 4; ++q) {
      f32x4 bq = *reinterpret_cast<const f32x4*>(bias + wr * 64 + mt * 32 + q * 8 + h * 4);
#pragma unroll
      for (int nt = 0; nt < 2; ++nt)
#pragma unroll
        for (int r = 0; r < 4; ++r)
          acc[mt][nt][q * 4 + r] = bq[r];
    }

  const char* wb = (const char*)wblk;
  const unsigned aoff = (unsigned)(((wr * 64 + n) * 16 + h * 8) * 2);
  const char* rA = (const char*)srcA + (unsigned)((wc * 64 + n) * PAB);

#define LOAD_A(KK, A0, A1) do {                                      \
    const char* ap_ = wb + (aoff + (unsigned)((KK) * 8192));         \
    A0 = *reinterpret_cast<const short8*>(ap_);                      \
    A1 = *reinterpret_cast<const short8*>(ap_ + 1024);               \
  } while (0)
#define LOAD_B(KK, B0, B1) do {                                      \
    unsigned off_ = ((unsigned)((KK) * 32 + h * 16)) ^ swz;          \
    const char* p_ = rA + off_;                                      \
    B0 = *reinterpret_cast<const short8*>(p_);                       \
    B1 = *reinterpret_cast<const short8*>(p_ + 32 * PAB);            \
  } while (0)
#define MFMA4(A0, A1, B0, B1) do {                                   \
    acc[0][0] = mfma32(A0, B0, acc[0][0]);                           \
    acc[0][1] = mfma32(A0, B1, acc[0][1]);                           \
    acc[1][0] = mfma32(A1, B0, acc[1][0]);                           \
    acc[1][1] = mfma32(A1, B1, acc[1][1]);                           \
  } while (0)

  short8 a0e, a1e, b0e, b1e;   // even-kk slots
  short8 a0o, a1o, b0o, b1o;   // odd-kk slots
  LOAD_B(0, b0e, b1e);
  LOAD_A(0, a0e, a1e);

#pragma unroll
  for (int kk = 0; kk < KKA; ++kk) {
    if ((kk & 1) == 0) {
      if (kk + 1 < KKA) {
        LOAD_B(kk + 1, b0o, b1o);
        LOAD_A(kk + 1, a0o, a1o);
      }
      __builtin_amdgcn_sched_barrier(0);
      __builtin_amdgcn_s_setprio(1);
      MFMA4(a0e, a1e, b0e, b1e);
      __builtin_amdgcn_s_setprio(0);
      __builtin_amdgcn_sched_barrier(0);
    } else {
      if (kk + 1 < KKA) {
        LOAD_B(kk + 1, b0e, b1e);
        LOAD_A(kk + 1, a0e, a1e);
      }
      __builtin_amdgcn_sched_barrier(0);
      __builtin_amdgcn_s_setprio(1);
      MFMA4(a0o, a1o, b0o, b1o);
      __builtin_amdgcn_s_setprio(0);
      __builtin_amdgcn_sched_barrier(0);
    }
  }

  if (KKB > 0) {
    // Short tail (L5 skip-concat from emb): same pinned pattern, depth-1.
    const char* rB = (const char*)srcB + (unsigned)((wc * 64 + n) * 128);
#pragma unroll
    for (int kl = 0; kl < KKB; ++kl) {
      const char* ab2 = wb + (aoff + (unsigned)((KKA + kl) * 8192));
      short8 a0 = *reinterpret_cast<const short8*>(ab2);
      short8 a1 = *reinterpret_cast<const short8*>(ab2 + 1024);
      unsigned off = ((unsigned)(kl * 32 + h * 16)) ^ swz;
      const char* p = rB + off;
      short8 b0 = *reinterpret_cast<const short8*>(p);
      short8 b1 = *reinterpret_cast<const short8*>(p + 32 * 128);
      __builtin_amdgcn_s_setprio(1);
      MFMA4(a0, a1, b0, b1);
      __builtin_amdgcn_s_setprio(0);
    }
  }
#undef LOAD_A
#undef LOAD_B
#undef MFMA4

  if (RB) __syncthreads();   // all waves done reading src (aliases dst)
  // C row = pt = wc*64 + nt*32 + n (row&7 == n&7); col byte =
  // wr*128 + mt*64 + q*16 + h*8.
  char* d0 = (char*)dst + (unsigned)((wc * 64 + n) * 512);
#pragma unroll
  for (int mt = 0; mt < 2; ++mt)
#pragma unroll
    for (int q = 0; q < 4; ++q) {
      unsigned soff = ((unsigned)(wr * 128 + mt * 64 + q * 16 + h * 8)) ^ swz;
      char* sp = d0 + soff;
#pragma unroll
      for (int nt = 0; nt < 2; ++nt) {
        float x0 = fmaxf(acc[mt][nt][q * 4 + 0], 0.0f);
        float x1 = fmaxf(acc[mt][nt][q * 4 + 1], 0.0f);
        float x2 = fmaxf(acc[mt][nt][q * 4 + 2], 0.0f);
        float x3 = fmaxf(acc[mt][nt][q * 4 + 3], 0.0f);
        uint2 pr;
        pr.x = cvtpk(x0, x1);
        pr.y = cvtpk(x2, x3);
        *reinterpret_cast<uint2*>(sp + nt * 16384) = pr;   // pt row +nt*32
      }
    }
  __syncthreads();           // writes visible
}

__launch_bounds__(512, 4)
__global__ void mlp_mfma(const float* __restrict__ pts, long N,
                         BPtrs B, const float* __restrict__ b8,
                         const unsigned short* __restrict__ wpk,
                         float* __restrict__ out) {
  extern __shared__ unsigned short smem[];
  unsigned short* act = smem;            // 128 x 256 bf16 = 64 KB, swizzled
  unsigned short* emb = smem + 32768;    // 128 x 64  bf16 = 16 KB, swizzled
  const int tid = threadIdx.x;
  const int w = tid >> 6, lane = tid & 63;
  const int n = lane & 31, h = lane >> 5;
  const int wr = w >> 1, wc = w & 1;
  const unsigned swz = (unsigned)((n & 7) << 4);   // == (pt&7)<<4 for rows wc*64+nt*32+n
  const long pbase = (long)blockIdx.x * 128;

  // ---- embedding: thread t -> point t/4, features (t&3)*16..+15 -----------
  {
    const int pt = tid >> 2, fg = tid & 3;
    const long pg = pbase + pt;
    float c0 = 0.f, c1 = 0.f, c2 = 0.f;
    if (pg < N) {
      const float* pp = pts + pg * 3;
      // nontemporal: pts read once; don't churn weight lines out of L2.
      c0 = __builtin_nontemporal_load(pp);
      c1 = __builtin_nontemporal_load(pp + 1);
      c2 = __builtin_nontemporal_load(pp + 2);
    }
    float x0 = c0 * INV2PI, x1 = c1 * INV2PI, x2 = c2 * INV2PI;
    unsigned pk[8];
#pragma unroll
    for (int i = 0; i < 16; i += 2) {
      int f0 = fg * 16 + i;
      float v0 = embval(f0,     c0, c1, c2, x0, x1, x2);
      float v1 = embval(f0 + 1, c0, c1, c2, x0, x1, x2);
      pk[i >> 1] = cvtpk(v0, v1);
    }
    const unsigned sw = (unsigned)((pt & 7) << 4);
    char* rowp = (char*)emb + (unsigned)(pt * 128);
    *reinterpret_cast<uint4*>(rowp + (((unsigned)(fg * 32)) ^ sw)) =
        uint4{pk[0], pk[1], pk[2], pk[3]};
    *reinterpret_cast<uint4*>(rowp + (((unsigned)(fg * 32 + 16)) ^ sw)) =
        uint4{pk[4], pk[5], pk[6], pk[7]};
  }
  __syncthreads();

  do_layer32<4,  128, 0, false>(emb, nullptr, wpk + PK_L0, B.b[0], act, wr, wc, n, h, swz);
  do_layer32<16, 512, 0, true >(act, nullptr, wpk + PK_L1, B.b[1], act, wr, wc, n, h, swz);
  do_layer32<16, 512, 0, true >(act, nullptr, wpk + PK_L2, B.b[2], act, wr, wc, n, h, swz);
  do_layer32<16, 512, 0, true >(act, nullptr, wpk + PK_L3, B.b[3], act, wr, wc, n, h, swz);
  do_layer32<16, 512, 0, true >(act, nullptr, wpk + PK_L4, B.b[4], act, wr, wc, n, h, swz);
  do_layer32<16, 512, 4, true >(act, emb,     wpk + PK_L5, B.b[5], act, wr, wc, n, h, swz);
  do_layer32<16, 512, 0, true >(act, nullptr, wpk + PK_L6, B.b[6], act, wr, wc, n, h, swz);
  do_layer32<16, 512, 0, true >(act, nullptr, wpk + PK_L7, B.b[7], act, wr, wc, n, h, swz);

  // ---- final 256->4 via 16x16x32: wave w -> pts [16w,16w+16) --------------
  {
    const int l16 = lane & 15, quad = lane >> 4;
    const unsigned short* w8b = wpk + PK_W8 + (unsigned)(l16 * 256 + quad * 8);
    short8 wf[8];
#pragma unroll
    for (int kk = 0; kk < 8; ++kk)
      wf[kk] = *reinterpret_cast<const short8*>(w8b + kk * 32);
    f32x4 bb = *reinterpret_cast<const f32x4*>(b8);
    const int pt = w * 16 + l16;               // pt&7 == lane&7 == n&7
    const char* ba = (const char*)act + (unsigned)(pt * 512);
    f32x4 a4 = {0.f, 0.f, 0.f, 0.f};
#pragma unroll
    for (int kk = 0; kk < 8; ++kk) {
      unsigned off = ((unsigned)(kk * 64 + quad * 16)) ^ swz;
      short8 b = *reinterpret_cast<const short8*>(ba + off);
      a4 = mfma16(wf[kk], b, a4);
    }
    if (quad == 0) {
      long pg = pbase + pt;
      f32x4 v = a4 + bb;
      if (pg < N)
        __builtin_nontemporal_store(v, reinterpret_cast<f32x4*>(out + pg * 4));
    }
  }
}

// ---------------------------------------------------------------------------
// Fallback (ws too small or dyn-LDS attr refused): round-1 VALU kernel,
// fp32 weights, proven correct.
// ---------------------------------------------------------------------------
__device__ __forceinline__ unsigned pk2s(float a, float b) {
  return (unsigned)f2bf(a) | ((unsigned)f2bf(b) << 16);
}
__device__ __forceinline__ void fb_seg(const unsigned short* src, int kRows,
                                       const float* __restrict__ wr,
                                       int lane, int ps, float acc[4][16]) {
#pragma unroll 4
  for (int k = 0; k < kRows; ++k) {
    const float* p = wr + k * 256 + lane;
    float w0 = p[0], w1 = p[64], w2 = p[128], w3 = p[192];
    const uint4* xr = reinterpret_cast<const uint4*>(src + ((k << 6) + ps));
    uint4 q0 = xr[0], q1 = xr[1];
    float x[16];
    x[0] = bf_lo(q0.x);  x[1] = bf_hi(q0.x);  x[2] = bf_lo(q0.y);  x[3] = bf_hi(q0.y);
    x[4] = bf_lo(q0.z);  x[5] = bf_hi(q0.z);  x[6] = bf_lo(q0.w);  x[7] = bf_hi(q0.w);
    x[8] = bf_lo(q1.x);  x[9] = bf_hi(q1.x);  x[10] = bf_lo(q1.y); x[11] = bf_hi(q1.y);
    x[12] = bf_lo(q1.z); x[13] = bf_hi(q1.z); x[14] = bf_lo(q1.w); x[15] = bf_hi(q1.w);
#pragma unroll
    for (int pp = 0; pp < 16; ++pp) {
      acc[0][pp] = fmaf(w0, x[pp], acc[0][pp]);
      acc[1][pp] = fmaf(w1, x[pp], acc[1][pp]);
      acc[2][pp] = fmaf(w2, x[pp], acc[2][pp]);
      acc[3][pp] = fmaf(w3, x[pp], acc[3][pp]);
    }
  }
}
__device__ __forceinline__ void fb_layer(const unsigned short* srcA, int kA,
                                         const unsigned short* srcB, int kB,
                                         const float* wrA, const float* wrB,
                                         const float* bias,
                                         unsigned short* dst, int lane, int ps) {
  float acc[4][16];
#pragma unroll
  for (int jt = 0; jt < 4; ++jt) {
    float bb = bias[lane + (jt << 6)];
#pragma unroll
    for (int pp = 0; pp < 16; ++pp) acc[jt][pp] = bb;
  }
  fb_seg(srcA, kA, wrA, lane, ps, acc);
  if (srcB) fb_seg(srcB, kB, wrB, lane, ps, acc);
#pragma unroll
  for (int jt = 0; jt < 4; ++jt) {
    unsigned short* dr = dst + (((lane + (jt << 6)) << 6) + ps);
    float r[16];
#pragma unroll
    for (int pp = 0; pp < 16; ++pp) r[pp] = fmaxf(acc[jt][pp], 0.0f);
    uint4 a, b;
    a.x = pk2s(r[0], r[1]);   a.y = pk2s(r[2], r[3]);
    a.z = pk2s(r[4], r[5]);   a.w = pk2s(r[6], r[7]);
    b.x = pk2s(r[8], r[9]);   b.y = pk2s(r[10], r[11]);
    b.z = pk2s(r[12], r[13]); b.w = pk2s(r[14], r[15]);
    reinterpret_cast<uint4*>(dr)[0] = a;
    reinterpret_cast<uint4*>(dr)[1] = b;
  }
}
__launch_bounds__(256, 2)
__global__ void mlp_fallback(const float* __restrict__ pts, int N,
                             WPtrs W, BPtrs B,
                             const float* __restrict__ w8,
                             const float* __restrict__ b8,
                             float* __restrict__ out) {
  __shared__ unsigned short act[256 * 64];
  __shared__ unsigned short emb[64 * 64];
  const int lane = threadIdx.x & 63;
  const int ps = (threadIdx.x >> 6) << 4;
  const long pbase = (long)blockIdx.x * 64 + ps;
#pragma unroll
  for (int i = 0; i < 16; ++i) {
    int idx = (i << 6) + lane;
    int f = idx >> 4, pp = idx & 15;
    float v = 0.0f;
    if (f < 63) {
      float c = (pbase + pp < N) ? pts[(pbase + pp) * 3 + (f / 21)] : 0.0f;
      float x = c * INV2PI;
      v = embval(f, c, c, c, x, x, x);
    }
    emb[(f << 6) + ps + pp] = f2bf(v);
  }
  fb_layer(emb, 63, nullptr, 0, W.w[0], nullptr, B.b[0], act, lane, ps);
#pragma unroll 1
  for (int l = 1; l <= 4; ++l)
    fb_layer(act, 256, nullptr, 0, W.w[l], nullptr, B.b[l], act, lane, ps);
  fb_layer(act, 256, emb, 63, W.w[5], W.w[5] + 256 * 256, B.b[5], act, lane, ps);
#pragma unroll 1
  for (int l = 6; l <= 7; ++l)
    fb_layer(act, 256, nullptr, 0, W.w[l], nullptr, B.b[l], act, lane, ps);
  {
    const int pp = lane & 15, cc = lane >> 4;
    float a = b8[cc];
#pragma unroll 4
    for (int k = 0; k < 256; ++k)
      a = fmaf(bf_lo((unsigned)act[(k << 6) + ps + pp]), w8[(k << 2) + cc], a);
    if (pbase + pp < N) out[(pbase + pp) * 4 + cc] = a;
  }
}

extern "C" void kernel_launch(void* const* d_in, const int* in_sizes, int n_in,
                              void* d_out, int out_size, void* d_ws, size_t ws_size,
                              hipStream_t stream) {
  const float* pts = (const float*)d_in[0];
  WPtrs W; BPtrs B;
  for (int i = 0; i < 8; ++i) {
    W.w[i] = (const float*)d_in[1 + 2 * i];
    B.b[i] = (const float*)d_in[2 + 2 * i];
  }
  const float* w8 = (const float*)d_in[17];
  const float* b8 = (const float*)d_in[18];
  float* out = (float*)d_out;
  const long N = in_sizes[0] / 3;

  const size_t need = (size_t)PK_TOTAL * sizeof(unsigned short);
  if (ws_size >= need) {
    // 80 KB dynamic LDS (act 64K + emb 16K): opt in once. Host-side, not a
    // stream op -> safe under graph capture.
    static hipError_t attr_err = hipFuncSetAttribute(
        reinterpret_cast<const void*>(mlp_mfma),
        hipFuncAttributeMaxDynamicSharedMemorySize, 81920);
    if (attr_err == hipSuccess) {
      unsigned short* wpk = (unsigned short*)d_ws;
      pack_weights<<<1936, 256, 0, stream>>>(W, w8, wpk);
      mlp_mfma<<<(int)((N + 127) / 128), 512, 81920, stream>>>(pts, N, B, b8, wpk, out);
      return;
    }
  }
  mlp_fallback<<<(int)((N + 63) / 64), 256, 0, stream>>>(pts, (int)N, W, B, w8, b8, out);
}

// Round 13
// 558.351 us; speedup vs baseline: 1.1626x; 1.1626x over previous
//
#include <hip/hip_runtime.h>
#include <math.h>

// ---------------------------------------------------------------------------
// Round 16: r10 champion (489us; r12/r13/r14/r15 all reverted) + 5-bit act
// LDS swizzle. r15 postmortem: launch_bounds(512,4) spilled (570MB scratch
// traffic) -- and r4 already proves 4 waves/SIMD loses even without spill.
// NEW evidence-read: SQ_LDS_BANK_CONFLICT 4.93e7 was wrongly dismissed as
// intrinsic. Bank math: B-read lanes hit only 8 distinct 16B slots (3-bit
// XOR key) -> 8 lanes/bank/pass = 8-way conflict (2.94x per m136). Act rows
// are 512B = 32 slots: extend key to (row&31)<<4 -> 32 distinct slots ->
// 2 lanes/bank = free. Writes fixed identically. emb keeps 3-bit key (128B
// rows); final layer re-keys per pt&31. Success signature: conflicts <=1.5e7.
// Numerics unchanged: bf16 W+act, fp32 acc (absmax ~3.9e-3 vs thr 1.148e-2).
// ---------------------------------------------------------------------------

typedef __attribute__((ext_vector_type(8))) short short8;
typedef __attribute__((ext_vector_type(4))) float f32x4;
typedef __attribute__((ext_vector_type(16))) float f32x16;

struct WPtrs { const float* w[8]; };
struct BPtrs { const float* b[8]; };

#define INV2PI 0.15915494309189533577f

// kk-block (K=16) offsets in elems (kkg * 4096):
// L0: 4kk @0, L1-L4: 16kk @4/20/36/52, L5: 20kk @68, L6: 16kk @88, L7 @104.
#define PK_L0 0
#define PK_L1 16384
#define PK_L2 81920
#define PK_L3 147456
#define PK_L4 212992
#define PK_L5 278528
#define PK_L6 360448
#define PK_L7 425984
#define PK_W8 491520           // [j=0..15][k=0..255]
#define PK_TOTAL 495616

__device__ __forceinline__ unsigned short f2bf(float v) {
  unsigned u = __float_as_uint(v);
  u = u + 0x7fffu + ((u >> 16) & 1u);
  return (unsigned short)(u >> 16);
}
__device__ __forceinline__ float bf_lo(unsigned u) { return __uint_as_float(u << 16); }
__device__ __forceinline__ float bf_hi(unsigned u) { return __uint_as_float(u & 0xffff0000u); }

__device__ __forceinline__ unsigned cvtpk(float a, float b) {
#if __has_builtin(__builtin_amdgcn_cvt_pk_bf16_f32)
  typedef __attribute__((ext_vector_type(2))) __bf16 bf16x2_t;
  bf16x2_t r = __builtin_amdgcn_cvt_pk_bf16_f32(a, b);
  return __builtin_bit_cast(unsigned, r);
#else
  unsigned ua = __float_as_uint(a);
  ua += 0x7fffu + ((ua >> 16) & 1u);
  unsigned ub = __float_as_uint(b);
  ub += 0x7fffu + ((ub >> 16) & 1u);
#if __has_builtin(__builtin_amdgcn_perm)
  return __builtin_amdgcn_perm(ub, ua, 0x07060302u);
#else
  return (ua >> 16) | (ub & 0xffff0000u);
#endif
#endif
}

__device__ __forceinline__ float fractf_(float x) {
#if __has_builtin(__builtin_amdgcn_fract_f32)
  return __builtin_amdgcn_fract_f32(x);
#else
  return x - floorf(x);
#endif
}
__device__ __forceinline__ float sin_rev(float rev) {
#if __has_builtin(__builtin_amdgcn_sinf)
  return __builtin_amdgcn_sinf(rev);
#else
  return __sinf(rev * 6.283185307179586f);
#endif
}

__device__ __forceinline__ float embval(int f, float c0, float c1, float c2,
                                        float x0, float x1, float x2) {
  if (f >= 63) return 0.0f;
  int d = (f >= 21 ? 1 : 0) + (f >= 42 ? 1 : 0);
  int r = f - d * 21;
  float c = (d == 0) ? c0 : (d == 1 ? c1 : c2);
  float x = (d == 0) ? x0 : (d == 1 ? x1 : x2);
  bool isc = r > 10;
  int e = isc ? (r - 11) : (r - 1);
  float rev = fractf_(ldexpf(x, e) + (isc ? 0.25f : 0.0f));
  float s = sin_rev(rev);
  return (r == 0) ? c : s;
}

__device__ __forceinline__ f32x16 mfma32(short8 a, short8 b, f32x16 c) {
  return __builtin_amdgcn_mfma_f32_32x32x16_bf16(a, b, c, 0, 0, 0);
}
__device__ __forceinline__ f32x4 mfma16(short8 a, short8 b, f32x4 c) {
  return __builtin_amdgcn_mfma_f32_16x16x32_bf16(a, b, c, 0, 0, 0);
}

// ---------------------------------------------------------------------------
// Prologue: pack weights as [kk][ch 0..255][16] bf16 (+ W8 as [j16][k256]).
// ---------------------------------------------------------------------------
__global__ void pack_weights(WPtrs W, const float* __restrict__ w8,
                             unsigned short* __restrict__ out) {
  int idx = blockIdx.x * 256 + threadIdx.x;
  if (idx >= PK_TOTAL) return;
  float v;
  if (idx >= PK_W8) {
    int t = idx - PK_W8;
    int j = t >> 8, k = t & 255;
    v = (j < 4) ? w8[k * 4 + j] : 0.0f;
  } else {
    int e = idx & 15;
    int blk = idx >> 4;
    int ch = blk & 255;
    int kkg = blk >> 8;              // 0..119
    int l, kk0;
    if      (kkg < 4)   { l = 0; kk0 = 0;   }
    else if (kkg < 20)  { l = 1; kk0 = 4;   }
    else if (kkg < 36)  { l = 2; kk0 = 20;  }
    else if (kkg < 52)  { l = 3; kk0 = 36;  }
    else if (kkg < 68)  { l = 4; kk0 = 52;  }
    else if (kkg < 88)  { l = 5; kk0 = 68;  }
    else if (kkg < 104) { l = 6; kk0 = 88;  }
    else                { l = 7; kk0 = 104; }
    int k = (kkg - kk0) * 16 + e;
    const int realK[8] = {63, 256, 256, 256, 256, 319, 256, 256};
    v = (k < realK[l]) ? W.w[l][k * 256 + ch] : 0.0f;
  }
  out[idx] = f2bf(v);
}

// ---------------------------------------------------------------------------
// One layer via 32x32x16, 128 points. Wave w: out-ch [64w,64w+64) x 128 pts.
// Full-unroll kk; named even/odd ping-pong slots for A (global) and B (LDS);
// sched_barrier(0)-pinned phases. swzS: XOR key for srcA reads; swzB: key
// for srcB (emb) reads; swzD: key for dst writes. Keys are row-keyed
// ((row&31)<<4 for act 512B rows, (row&7)<<4 for emb 128B rows) and rows
// 32 apart share (row&31), so one per-lane key serves all 4 row groups.
// RB: barrier before writeback (src aliases dst).
// ---------------------------------------------------------------------------
template <int KKA, int PAB, int KKB, bool RB>
__device__ __forceinline__ void do_layer32(
    const unsigned short* srcA, const unsigned short* srcB,
    const unsigned short* __restrict__ wblk,
    const float* __restrict__ bias,
    unsigned short* dst, int w, int n, int h,
    unsigned swzS, unsigned swzB, unsigned swzD) {
  f32x16 acc[2][4];
#pragma unroll
  for (int mt = 0; mt < 2; ++mt)
#pragma unroll
    for (int q = 0; q < 4; ++q) {
      f32x4 bq = *reinterpret_cast<const f32x4*>(bias + w * 64 + mt * 32 + q * 8 + h * 4);
#pragma unroll
      for (int nt = 0; nt < 4; ++nt)
#pragma unroll
        for (int r = 0; r < 4; ++r)
          acc[mt][nt][q * 4 + r] = bq[r];
    }

  const char* wb = (const char*)wblk;
  const unsigned aoff = (unsigned)(((w * 64 + n) * 16 + h * 8) * 2);
  const char* rA = (const char*)srcA + (unsigned)(n * PAB);

#define LOAD_A(KK, A0, A1) do {                                      \
    const char* ap_ = wb + (aoff + (unsigned)((KK) * 8192));         \
    A0 = *reinterpret_cast<const short8*>(ap_);                      \
    A1 = *reinterpret_cast<const short8*>(ap_ + 1024);               \
  } while (0)
#define LOAD_B(KK, B0, B1, B2, B3) do {                              \
    unsigned off_ = ((unsigned)((KK) * 32 + h * 16)) ^ swzS;         \
    const char* p_ = rA + off_;                                      \
    B0 = *reinterpret_cast<const short8*>(p_);                       \
    B1 = *reinterpret_cast<const short8*>(p_ + 32 * PAB);            \
    B2 = *reinterpret_cast<const short8*>(p_ + 64 * PAB);            \
    B3 = *reinterpret_cast<const short8*>(p_ + 96 * PAB);            \
  } while (0)
#define MFMA8(A0, A1, B0, B1, B2, B3) do {                           \
    acc[0][0] = mfma32(A0, B0, acc[0][0]);                           \
    acc[0][1] = mfma32(A0, B1, acc[0][1]);                           \
    acc[0][2] = mfma32(A0, B2, acc[0][2]);                           \
    acc[0][3] = mfma32(A0, B3, acc[0][3]);                           \
    acc[1][0] = mfma32(A1, B0, acc[1][0]);                           \
    acc[1][1] = mfma32(A1, B1, acc[1][1]);                           \
    acc[1][2] = mfma32(A1, B2, acc[1][2]);                           \
    acc[1][3] = mfma32(A1, B3, acc[1][3]);                           \
  } while (0)

  short8 a0e, a1e, b0e, b1e, b2e, b3e;   // even-kk slots
  short8 a0o, a1o, b0o, b1o, b2o, b3o;   // odd-kk slots
  LOAD_B(0, b0e, b1e, b2e, b3e);
  LOAD_A(0, a0e, a1e);

#pragma unroll
  for (int kk = 0; kk < KKA; ++kk) {
    if ((kk & 1) == 0) {
      if (kk + 1 < KKA) {
        LOAD_B(kk + 1, b0o, b1o, b2o, b3o);
        LOAD_A(kk + 1, a0o, a1o);
      }
      __builtin_amdgcn_sched_barrier(0);
      __builtin_amdgcn_s_setprio(1);
      MFMA8(a0e, a1e, b0e, b1e, b2e, b3e);
      __builtin_amdgcn_s_setprio(0);
      __builtin_amdgcn_sched_barrier(0);
    } else {
      if (kk + 1 < KKA) {
        LOAD_B(kk + 1, b0e, b1e, b2e, b3e);
        LOAD_A(kk + 1, a0e, a1e);
      }
      __builtin_amdgcn_sched_barrier(0);
      __builtin_amdgcn_s_setprio(1);
      MFMA8(a0o, a1o, b0o, b1o, b2o, b3o);
      __builtin_amdgcn_s_setprio(0);
      __builtin_amdgcn_sched_barrier(0);
    }
  }

  if (KKB > 0) {
    // Short tail (L5 skip-concat from emb): same pinned pattern, depth-1.
    const char* rB = (const char*)srcB + (unsigned)(n * 128);
#pragma unroll
    for (int kl = 0; kl < KKB; ++kl) {
      const char* ab2 = wb + (aoff + (unsigned)((KKA + kl) * 8192));
      short8 a0 = *reinterpret_cast<const short8*>(ab2);
      short8 a1 = *reinterpret_cast<const short8*>(ab2 + 1024);
      unsigned off = ((unsigned)(kl * 32 + h * 16)) ^ swzB;
      const char* p = rB + off;
      short8 b0 = *reinterpret_cast<const short8*>(p);
      short8 b1 = *reinterpret_cast<const short8*>(p + 32 * 128);
      short8 b2 = *reinterpret_cast<const short8*>(p + 64 * 128);
      short8 b3 = *reinterpret_cast<const short8*>(p + 96 * 128);
      __builtin_amdgcn_s_setprio(1);
      MFMA8(a0, a1, b0, b1, b2, b3);
      __builtin_amdgcn_s_setprio(0);
    }
  }
#undef LOAD_A
#undef LOAD_B
#undef MFMA8

  if (RB) __syncthreads();   // all waves done reading src (aliases dst)
  char* d0 = (char*)dst + (unsigned)(n * 512);
#pragma unroll
  for (int mt = 0; mt < 2; ++mt)
#pragma unroll
    for (int q = 0; q < 4; ++q) {
      unsigned soff = ((unsigned)(w * 128 + mt * 64 + q * 16 + h * 8)) ^ swzD;
      char* sp = d0 + soff;
#pragma unroll
      for (int nt = 0; nt < 4; ++nt) {
        float x0 = fmaxf(acc[mt][nt][q * 4 + 0], 0.0f);
        float x1 = fmaxf(acc[mt][nt][q * 4 + 1], 0.0f);
        float x2 = fmaxf(acc[mt][nt][q * 4 + 2], 0.0f);
        float x3 = fmaxf(acc[mt][nt][q * 4 + 3], 0.0f);
        uint2 pr;
        pr.x = cvtpk(x0, x1);
        pr.y = cvtpk(x2, x3);
        *reinterpret_cast<uint2*>(sp + nt * 16384) = pr;   // row nt*32+n
      }
    }
  __syncthreads();           // writes visible
}

__launch_bounds__(256, 2)
__global__ void mlp_mfma(const float* __restrict__ pts, long N,
                         BPtrs B, const float* __restrict__ b8,
                         const unsigned short* __restrict__ wpk,
                         float* __restrict__ out) {
  extern __shared__ unsigned short smem[];
  unsigned short* act = smem;            // 128 x 256 bf16 = 64 KB, 5-bit swz
  unsigned short* emb = smem + 32768;    // 128 x 64  bf16 = 16 KB, 3-bit swz
  const int tid = threadIdx.x;
  const int w = tid >> 6, lane = tid & 63;
  const int n = lane & 31, h = lane >> 5;
  const unsigned swzA = (unsigned)((n & 31) << 4);  // act key: row&31 (==n for rows n+32k)
  const unsigned swzE = (unsigned)((n & 7) << 4);   // emb key: row&7
  const long pbase = (long)blockIdx.x * 128;

  // ---- embedding: thread t -> point t/2, features (t&1)*32..+31 -----------
  {
    const int pt = tid >> 1, fg = tid & 1;
    const long pg = pbase + pt;
    float c0 = 0.f, c1 = 0.f, c2 = 0.f;
    if (pg < N) {
      const float* pp = pts + pg * 3;
      // nontemporal: pts read once; don't churn weight lines out of L2.
      c0 = __builtin_nontemporal_load(pp);
      c1 = __builtin_nontemporal_load(pp + 1);
      c2 = __builtin_nontemporal_load(pp + 2);
    }
    float x0 = c0 * INV2PI, x1 = c1 * INV2PI, x2 = c2 * INV2PI;
    const unsigned sw = (unsigned)((pt & 7) << 4);
    char* rowp = (char*)emb + (unsigned)(pt * 128);
#pragma unroll
    for (int jb = 0; jb < 2; ++jb) {
      unsigned pk[8];
#pragma unroll
      for (int i = 0; i < 16; i += 2) {
        int f0 = fg * 32 + jb * 16 + i;
        float v0 = embval(f0,     c0, c1, c2, x0, x1, x2);
        float v1 = embval(f0 + 1, c0, c1, c2, x0, x1, x2);
        pk[i >> 1] = cvtpk(v0, v1);
      }
      unsigned base = (unsigned)(fg * 64 + jb * 32);
      *reinterpret_cast<uint4*>(rowp + (base ^ sw)) =
          uint4{pk[0], pk[1], pk[2], pk[3]};
      *reinterpret_cast<uint4*>(rowp + ((base + 16) ^ sw)) =
          uint4{pk[4], pk[5], pk[6], pk[7]};
    }
  }
  __syncthreads();

  do_layer32<4,  128, 0, false>(emb, nullptr, wpk + PK_L0, B.b[0], act, w, n, h, swzE, 0,    swzA);
  do_layer32<16, 512, 0, true >(act, nullptr, wpk + PK_L1, B.b[1], act, w, n, h, swzA, 0,    swzA);
  do_layer32<16, 512, 0, true >(act, nullptr, wpk + PK_L2, B.b[2], act, w, n, h, swzA, 0,    swzA);
  do_layer32<16, 512, 0, true >(act, nullptr, wpk + PK_L3, B.b[3], act, w, n, h, swzA, 0,    swzA);
  do_layer32<16, 512, 0, true >(act, nullptr, wpk + PK_L4, B.b[4], act, w, n, h, swzA, 0,    swzA);
  do_layer32<16, 512, 4, true >(act, emb,     wpk + PK_L5, B.b[5], act, w, n, h, swzA, swzE, swzA);
  do_layer32<16, 512, 0, true >(act, nullptr, wpk + PK_L6, B.b[6], act, w, n, h, swzA, 0,    swzA);
  do_layer32<16, 512, 0, true >(act, nullptr, wpk + PK_L7, B.b[7], act, w, n, h, swzA, 0,    swzA);

  // ---- final 256->4 via 16x16x32: wave w -> pts [32w,32w+32), 2 x 16 ------
  {
    const int l16 = lane & 15, quad = lane >> 4;
    const unsigned short* w8b = wpk + PK_W8 + (unsigned)(l16 * 256 + quad * 8);
    short8 wf[8];
#pragma unroll
    for (int kk = 0; kk < 8; ++kk)
      wf[kk] = *reinterpret_cast<const short8*>(w8b + kk * 32);
    f32x4 bb = *reinterpret_cast<const f32x4*>(b8);
#pragma unroll
    for (int it = 0; it < 2; ++it) {
      const int pt = w * 32 + it * 16 + l16;
      // act key for row pt: (pt&31)<<4 == ((it*16 + l16)&31)<<4
      const unsigned swzF = (unsigned)(((it * 16 + l16) & 31) << 4);
      const char* ba = (const char*)act + (unsigned)(pt * 512);
      f32x4 a4 = {0.f, 0.f, 0.f, 0.f};
#pragma unroll
      for (int kk = 0; kk < 8; ++kk) {
        unsigned off = ((unsigned)(kk * 64 + quad * 16)) ^ swzF;
        short8 b = *reinterpret_cast<const short8*>(ba + off);
        a4 = mfma16(wf[kk], b, a4);
      }
      if (quad == 0) {
        long pg = pbase + pt;
        f32x4 v = a4 + bb;
        if (pg < N)
          __builtin_nontemporal_store(v, reinterpret_cast<f32x4*>(out + pg * 4));
      }
    }
  }
}

// ---------------------------------------------------------------------------
// Fallback (ws too small or dyn-LDS attr refused): round-1 VALU kernel,
// fp32 weights, proven correct.
// ---------------------------------------------------------------------------
__device__ __forceinline__ unsigned pk2s(float a, float b) {
  return (unsigned)f2bf(a) | ((unsigned)f2bf(b) << 16);
}
__device__ __forceinline__ void fb_seg(const unsigned short* src, int kRows,
                                       const float* __restrict__ wr,
                                       int lane, int ps, float acc[4][16]) {
#pragma unroll 4
  for (int k = 0; k < kRows; ++k) {
    const float* p = wr + k * 256 + lane;
    float w0 = p[0], w1 = p[64], w2 = p[128], w3 = p[192];
    const uint4* xr = reinterpret_cast<const uint4*>(src + ((k << 6) + ps));
    uint4 q0 = xr[0], q1 = xr[1];
    float x[16];
    x[0] = bf_lo(q0.x);  x[1] = bf_hi(q0.x);  x[2] = bf_lo(q0.y);  x[3] = bf_hi(q0.y);
    x[4] = bf_lo(q0.z);  x[5] = bf_hi(q0.z);  x[6] = bf_lo(q0.w);  x[7] = bf_hi(q0.w);
    x[8] = bf_lo(q1.x);  x[9] = bf_hi(q1.x);  x[10] = bf_lo(q1.y); x[11] = bf_hi(q1.y);
    x[12] = bf_lo(q1.z); x[13] = bf_hi(q1.z); x[14] = bf_lo(q1.w); x[15] = bf_hi(q1.w);
#pragma unroll
    for (int pp = 0; pp < 16; ++pp) {
      acc[0][pp] = fmaf(w0, x[pp], acc[0][pp]);
      acc[1][pp] = fmaf(w1, x[pp], acc[1][pp]);
      acc[2][pp] = fmaf(w2, x[pp], acc[2][pp]);
      acc[3][pp] = fmaf(w3, x[pp], acc[3][pp]);
    }
  }
}
__device__ __forceinline__ void fb_layer(const unsigned short* srcA, int kA,
                                         const unsigned short* srcB, int kB,
                                         const float* wrA, const float* wrB,
                                         const float* bias,
                                         unsigned short* dst, int lane, int ps) {
  float acc[4][16];
#pragma unroll
  for (int jt = 0; jt < 4; ++jt) {
    float bb = bias[lane + (jt << 6)];
#pragma unroll
    for (int pp = 0; pp < 16; ++pp) acc[jt][pp] = bb;
  }
  fb_seg(srcA, kA, wrA, lane, ps, acc);
  if (srcB) fb_seg(srcB, kB, wrB, lane, ps, acc);
#pragma unroll
  for (int jt = 0; jt < 4; ++jt) {
    unsigned short* dr = dst + (((lane + (jt << 6)) << 6) + ps);
    float r[16];
#pragma unroll
    for (int pp = 0; pp < 16; ++pp) r[pp] = fmaxf(acc[jt][pp], 0.0f);
    uint4 a, b;
    a.x = pk2s(r[0], r[1]);   a.y = pk2s(r[2], r[3]);
    a.z = pk2s(r[4], r[5]);   a.w = pk2s(r[6], r[7]);
    b.x = pk2s(r[8], r[9]);   b.y = pk2s(r[10], r[11]);
    b.z = pk2s(r[12], r[13]); b.w = pk2s(r[14], r[15]);
    reinterpret_cast<uint4*>(dr)[0] = a;
    reinterpret_cast<uint4*>(dr)[1] = b;
  }
}
__launch_bounds__(256, 2)
__global__ void mlp_fallback(const float* __restrict__ pts, int N,
                             WPtrs W, BPtrs B,
                             const float* __restrict__ w8,
                             const float* __restrict__ b8,
                             float* __restrict__ out) {
  __shared__ unsigned short act[256 * 64];
  __shared__ unsigned short emb[64 * 64];
  const int lane = threadIdx.x & 63;
  const int ps = (threadIdx.x >> 6) << 4;
  const long pbase = (long)blockIdx.x * 64 + ps;
#pragma unroll
  for (int i = 0; i < 16; ++i) {
    int idx = (i << 6) + lane;
    int f = idx >> 4, pp = idx & 15;
    float v = 0.0f;
    if (f < 63) {
      float c = (pbase + pp < N) ? pts[(pbase + pp) * 3 + (f / 21)] : 0.0f;
      float x = c * INV2PI;
      v = embval(f, c, c, c, x, x, x);
    }
    emb[(f << 6) + ps + pp] = f2bf(v);
  }
  fb_layer(emb, 63, nullptr, 0, W.w[0], nullptr, B.b[0], act, lane, ps);
#pragma unroll 1
  for (int l = 1; l <= 4; ++l)
    fb_layer(act, 256, nullptr, 0, W.w[l], nullptr, B.b[l], act, lane, ps);
  fb_layer(act, 256, emb, 63, W.w[5], W.w[5] + 256 * 256, B.b[5], act, lane, ps);
#pragma unroll 1
  for (int l = 6; l <= 7; ++l)
    fb_layer(act, 256, nullptr, 0, W.w[l], nullptr, B.b[l], act, lane, ps);
  {
    const int pp = lane & 15, cc = lane >> 4;
    float a = b8[cc];
#pragma unroll 4
    for (int k = 0; k < 256; ++k)
      a = fmaf(bf_lo((unsigned)act[(k << 6) + ps + pp]), w8[(k << 2) + cc], a);
    if (pbase + pp < N) out[(pbase + pp) * 4 + cc] = a;
  }
}

extern "C" void kernel_launch(void* const* d_in, const int* in_sizes, int n_in,
                              void* d_out, int out_size, void* d_ws, size_t ws_size,
                              hipStream_t stream) {
  const float* pts = (const float*)d_in[0];
  WPtrs W; BPtrs B;
  for (int i = 0; i < 8; ++i) {
    W.w[i] = (const float*)d_in[1 + 2 * i];
    B.b[i] = (const float*)d_in[2 + 2 * i];
  }
  const float* w8 = (const float*)d_in[17];
  const float* b8 = (const float*)d_in[18];
  float* out = (float*)d_out;
  const long N = in_sizes[0] / 3;

  const size_t need = (size_t)PK_TOTAL * sizeof(unsigned short);
  if (ws_size >= need) {
    // 80 KB dynamic LDS (act 64K + emb 16K): opt in once. Host-side, not a
    // stream op -> safe under graph capture.
    static hipError_t attr_err = hipFuncSetAttribute(
        reinterpret_cast<const void*>(mlp_mfma),
        hipFuncAttributeMaxDynamicSharedMemorySize, 81920);
    if (attr_err == hipSuccess) {
      unsigned short* wpk = (unsigned short*)d_ws;
      pack_weights<<<1936, 256, 0, stream>>>(W, w8, wpk);
      mlp_mfma<<<(int)((N + 127) / 128), 256, 81920, stream>>>(pts, N, B, b8, wpk, out);
      return;
    }
  }
  mlp_fallback<<<(int)((N + 63) / 64), 256, 0, stream>>>(pts, (int)N, W, B, w8, b8, out);
}

// Round 14
// 531.652 us; speedup vs baseline: 1.2210x; 1.0502x over previous
//
#include <hip/hip_runtime.h>
#include <math.h>

// ---------------------------------------------------------------------------
// Round 17: explicit counted s_waitcnt via inline-asm loads (r16 champion
// envelope + 5-bit swizzle kept; conflicts 4.9e7->1.9e7 proven, timing null).
// Residual model: wall-phase ~1000cy vs 512cy MFMA demand; depth-2-null (r12)
// and merge-negative (r13) are BOTH retrodicted if the compiler emits
// drain-style waitcnt before each MFMA cluster (prefetch can't help if every
// phase drains). Pins control order, not wait VALUES. Fix: K-loop A/B loads
// in inline asm (compiler inserts no waits for asm outputs); the only waits
// are explicit s_waitcnt vmcnt(2) lgkmcnt(4) (next phase's 2 global + 4 ds
// stay in flight; DS/VMEM count in issue order so (4,2) is exact), each
// followed by sched_barrier(0) (rule 18: MFMA hoist hazard). Pre-loop drain
// (vmcnt0/lgkm0 + pin) isolates bias-load counts. Last phase waits (0,0).
// Numerics unchanged: bf16 W+act, fp32 acc (absmax ~3.9e-3 vs thr 1.148e-2).
// ---------------------------------------------------------------------------

typedef __attribute__((ext_vector_type(8))) short short8;
typedef __attribute__((ext_vector_type(4))) float f32x4;
typedef __attribute__((ext_vector_type(16))) float f32x16;

struct WPtrs { const float* w[8]; };
struct BPtrs { const float* b[8]; };

#define INV2PI 0.15915494309189533577f

// kk-block (K=16) offsets in elems (kkg * 4096):
// L0: 4kk @0, L1-L4: 16kk @4/20/36/52, L5: 20kk @68, L6: 16kk @88, L7 @104.
#define PK_L0 0
#define PK_L1 16384
#define PK_L2 81920
#define PK_L3 147456
#define PK_L4 212992
#define PK_L5 278528
#define PK_L6 360448
#define PK_L7 425984
#define PK_W8 491520           // [j=0..15][k=0..255]
#define PK_TOTAL 495616

__device__ __forceinline__ unsigned short f2bf(float v) {
  unsigned u = __float_as_uint(v);
  u = u + 0x7fffu + ((u >> 16) & 1u);
  return (unsigned short)(u >> 16);
}
__device__ __forceinline__ float bf_lo(unsigned u) { return __uint_as_float(u << 16); }
__device__ __forceinline__ float bf_hi(unsigned u) { return __uint_as_float(u & 0xffff0000u); }

__device__ __forceinline__ unsigned cvtpk(float a, float b) {
#if __has_builtin(__builtin_amdgcn_cvt_pk_bf16_f32)
  typedef __attribute__((ext_vector_type(2))) __bf16 bf16x2_t;
  bf16x2_t r = __builtin_amdgcn_cvt_pk_bf16_f32(a, b);
  return __builtin_bit_cast(unsigned, r);
#else
  unsigned ua = __float_as_uint(a);
  ua += 0x7fffu + ((ua >> 16) & 1u);
  unsigned ub = __float_as_uint(b);
  ub += 0x7fffu + ((ub >> 16) & 1u);
#if __has_builtin(__builtin_amdgcn_perm)
  return __builtin_amdgcn_perm(ub, ua, 0x07060302u);
#else
  return (ua >> 16) | (ub & 0xffff0000u);
#endif
#endif
}

__device__ __forceinline__ float fractf_(float x) {
#if __has_builtin(__builtin_amdgcn_fract_f32)
  return __builtin_amdgcn_fract_f32(x);
#else
  return x - floorf(x);
#endif
}
__device__ __forceinline__ float sin_rev(float rev) {
#if __has_builtin(__builtin_amdgcn_sinf)
  return __builtin_amdgcn_sinf(rev);
#else
  return __sinf(rev * 6.283185307179586f);
#endif
}

__device__ __forceinline__ float embval(int f, float c0, float c1, float c2,
                                        float x0, float x1, float x2) {
  if (f >= 63) return 0.0f;
  int d = (f >= 21 ? 1 : 0) + (f >= 42 ? 1 : 0);
  int r = f - d * 21;
  float c = (d == 0) ? c0 : (d == 1 ? c1 : c2);
  float x = (d == 0) ? x0 : (d == 1 ? x1 : x2);
  bool isc = r > 10;
  int e = isc ? (r - 11) : (r - 1);
  float rev = fractf_(ldexpf(x, e) + (isc ? 0.25f : 0.0f));
  float s = sin_rev(rev);
  return (r == 0) ? c : s;
}

__device__ __forceinline__ f32x16 mfma32(short8 a, short8 b, f32x16 c) {
  return __builtin_amdgcn_mfma_f32_32x32x16_bf16(a, b, c, 0, 0, 0);
}
__device__ __forceinline__ f32x4 mfma16(short8 a, short8 b, f32x4 c) {
  return __builtin_amdgcn_mfma_f32_16x16x32_bf16(a, b, c, 0, 0, 0);
}

// ---------------------------------------------------------------------------
// Prologue: pack weights as [kk][ch 0..255][16] bf16 (+ W8 as [j16][k256]).
// ---------------------------------------------------------------------------
__global__ void pack_weights(WPtrs W, const float* __restrict__ w8,
                             unsigned short* __restrict__ out) {
  int idx = blockIdx.x * 256 + threadIdx.x;
  if (idx >= PK_TOTAL) return;
  float v;
  if (idx >= PK_W8) {
    int t = idx - PK_W8;
    int j = t >> 8, k = t & 255;
    v = (j < 4) ? w8[k * 4 + j] : 0.0f;
  } else {
    int e = idx & 15;
    int blk = idx >> 4;
    int ch = blk & 255;
    int kkg = blk >> 8;              // 0..119
    int l, kk0;
    if      (kkg < 4)   { l = 0; kk0 = 0;   }
    else if (kkg < 20)  { l = 1; kk0 = 4;   }
    else if (kkg < 36)  { l = 2; kk0 = 20;  }
    else if (kkg < 52)  { l = 3; kk0 = 36;  }
    else if (kkg < 68)  { l = 4; kk0 = 52;  }
    else if (kkg < 88)  { l = 5; kk0 = 68;  }
    else if (kkg < 104) { l = 6; kk0 = 88;  }
    else                { l = 7; kk0 = 104; }
    int k = (kkg - kk0) * 16 + e;
    const int realK[8] = {63, 256, 256, 256, 256, 319, 256, 256};
    v = (k < realK[l]) ? W.w[l][k * 256 + ch] : 0.0f;
  }
  out[idx] = f2bf(v);
}

// ---------------------------------------------------------------------------
// One layer via 32x32x16, 128 points. Wave w: out-ch [64w,64w+64) x 128 pts.
// K-loop loads via INLINE ASM (no compiler waits); explicit counted
// s_waitcnt vmcnt(2) lgkmcnt(4) per phase (+ sched_barrier(0) per rule 18).
// swzS/swzB/swzD as in r16 (5-bit act keys, 3-bit emb). RB: barrier before
// writeback (src aliases dst).
// ---------------------------------------------------------------------------
template <int KKA, int PAB, int KKB, bool RB>
__device__ __forceinline__ void do_layer32(
    const unsigned short* srcA, const unsigned short* srcB,
    const unsigned short* __restrict__ wblk,
    const float* __restrict__ bias,
    unsigned short* dst, int w, int n, int h,
    unsigned swzS, unsigned swzB, unsigned swzD) {
  f32x16 acc[2][4];
#pragma unroll
  for (int mt = 0; mt < 2; ++mt)
#pragma unroll
    for (int q = 0; q < 4; ++q) {
      f32x4 bq = *reinterpret_cast<const f32x4*>(bias + w * 64 + mt * 32 + q * 8 + h * 4);
#pragma unroll
      for (int nt = 0; nt < 4; ++nt)
#pragma unroll
        for (int r = 0; r < 4; ++r)
          acc[mt][nt][q * 4 + r] = bq[r];
    }

  const char* wbA = (const char*)wblk + (unsigned)(((w * 64 + n) * 16 + h * 8) * 2);
  // LDS byte offset: generic shared addr low 32 bits = LDS offset (aperture
  // bits live in the high half on gfx9+; HK-proven truncation).
  const unsigned rA32 = (unsigned)(unsigned long long)srcA + (unsigned)(n * PAB);

#define ASM_LOAD_A(KK, A0, A1) do {                                       \
    const char* ap_ = wbA + (unsigned)((KK) * 8192);                      \
    asm volatile("global_load_dwordx4 %0, %1, off"                        \
                 : "=v"(A0) : "v"(ap_));                                  \
    asm volatile("global_load_dwordx4 %0, %1, off offset:1024"            \
                 : "=v"(A1) : "v"(ap_));                                  \
  } while (0)
#define ASM_LOAD_B(KK, B0, B1, B2, B3) do {                               \
    unsigned ba_ = rA32 + (((unsigned)((KK) * 32 + h * 16)) ^ swzS);      \
    asm volatile("ds_read_b128 %0, %1" : "=v"(B0) : "v"(ba_));            \
    asm volatile("ds_read_b128 %0, %1 offset:%2"                          \
                 : "=v"(B1) : "v"(ba_), "n"(32 * PAB));                   \
    asm volatile("ds_read_b128 %0, %1 offset:%2"                          \
                 : "=v"(B2) : "v"(ba_), "n"(64 * PAB));                   \
    asm volatile("ds_read_b128 %0, %1 offset:%2"                          \
                 : "=v"(B3) : "v"(ba_), "n"(96 * PAB));                   \
  } while (0)
#define MFMA8(A0, A1, B0, B1, B2, B3) do {                           \
    acc[0][0] = mfma32(A0, B0, acc[0][0]);                           \
    acc[0][1] = mfma32(A0, B1, acc[0][1]);                           \
    acc[0][2] = mfma32(A0, B2, acc[0][2]);                           \
    acc[0][3] = mfma32(A0, B3, acc[0][3]);                           \
    acc[1][0] = mfma32(A1, B0, acc[1][0]);                           \
    acc[1][1] = mfma32(A1, B1, acc[1][1]);                           \
    acc[1][2] = mfma32(A1, B2, acc[1][2]);                           \
    acc[1][3] = mfma32(A1, B3, acc[1][3]);                           \
  } while (0)
#define WAIT_COUNTED() do {                                          \
    asm volatile("s_waitcnt vmcnt(2) lgkmcnt(4)" ::: "memory");      \
  } while (0)
#define WAIT_ALL() do {                                              \
    asm volatile("s_waitcnt vmcnt(0) lgkmcnt(0)" ::: "memory");      \
  } while (0)

  short8 a0e, a1e, b0e, b1e, b2e, b3e;   // even-kk slots
  short8 a0o, a1o, b0o, b1o, b2o, b3o;   // odd-kk slots

  // Drain compiler-issued loads (bias) so explicit counts are exact.
  WAIT_ALL();
  __builtin_amdgcn_sched_barrier(0);

  ASM_LOAD_B(0, b0e, b1e, b2e, b3e);
  ASM_LOAD_A(0, a0e, a1e);

#pragma unroll
  for (int kk = 0; kk < KKA; ++kk) {
    if ((kk & 1) == 0) {
      if (kk + 1 < KKA) {
        ASM_LOAD_B(kk + 1, b0o, b1o, b2o, b3o);
        ASM_LOAD_A(kk + 1, a0o, a1o);
      }
    } else {
      if (kk + 1 < KKA) {
        ASM_LOAD_B(kk + 1, b0e, b1e, b2e, b3e);
        ASM_LOAD_A(kk + 1, a0e, a1e);
      }
    }
    if (kk + 1 < KKA) WAIT_COUNTED(); else WAIT_ALL();
    __builtin_amdgcn_sched_barrier(0);
    __builtin_amdgcn_s_setprio(1);
    if ((kk & 1) == 0) MFMA8(a0e, a1e, b0e, b1e, b2e, b3e);
    else               MFMA8(a0o, a1o, b0o, b1o, b2o, b3o);
    __builtin_amdgcn_s_setprio(0);
    __builtin_amdgcn_sched_barrier(0);
  }

  if (KKB > 0) {
    // Short tail (L5 skip-concat from emb): plain loads (counters drained).
    const char* rB = (const char*)srcB + (unsigned)(n * 128);
#pragma unroll
    for (int kl = 0; kl < KKB; ++kl) {
      const char* ab2 = wbA + (unsigned)((KKA + kl) * 8192);
      short8 a0 = *reinterpret_cast<const short8*>(ab2);
      short8 a1 = *reinterpret_cast<const short8*>(ab2 + 1024);
      unsigned off = ((unsigned)(kl * 32 + h * 16)) ^ swzB;
      const char* p = rB + off;
      short8 b0 = *reinterpret_cast<const short8*>(p);
      short8 b1 = *reinterpret_cast<const short8*>(p + 32 * 128);
      short8 b2 = *reinterpret_cast<const short8*>(p + 64 * 128);
      short8 b3 = *reinterpret_cast<const short8*>(p + 96 * 128);
      __builtin_amdgcn_s_setprio(1);
      MFMA8(a0, a1, b0, b1, b2, b3);
      __builtin_amdgcn_s_setprio(0);
    }
  }
#undef ASM_LOAD_A
#undef ASM_LOAD_B
#undef MFMA8
#undef WAIT_COUNTED
#undef WAIT_ALL

  if (RB) __syncthreads();   // all waves done reading src (aliases dst)
  char* d0 = (char*)dst + (unsigned)(n * 512);
#pragma unroll
  for (int mt = 0; mt < 2; ++mt)
#pragma unroll
    for (int q = 0; q < 4; ++q) {
      unsigned soff = ((unsigned)(w * 128 + mt * 64 + q * 16 + h * 8)) ^ swzD;
      char* sp = d0 + soff;
#pragma unroll
      for (int nt = 0; nt < 4; ++nt) {
        float x0 = fmaxf(acc[mt][nt][q * 4 + 0], 0.0f);
        float x1 = fmaxf(acc[mt][nt][q * 4 + 1], 0.0f);
        float x2 = fmaxf(acc[mt][nt][q * 4 + 2], 0.0f);
        float x3 = fmaxf(acc[mt][nt][q * 4 + 3], 0.0f);
        uint2 pr;
        pr.x = cvtpk(x0, x1);
        pr.y = cvtpk(x2, x3);
        *reinterpret_cast<uint2*>(sp + nt * 16384) = pr;   // row nt*32+n
      }
    }
  __syncthreads();           // writes visible
}

__launch_bounds__(256, 2)
__global__ void mlp_mfma(const float* __restrict__ pts, long N,
                         BPtrs B, const float* __restrict__ b8,
                         const unsigned short* __restrict__ wpk,
                         float* __restrict__ out) {
  extern __shared__ unsigned short smem[];
  unsigned short* act = smem;            // 128 x 256 bf16 = 64 KB, 5-bit swz
  unsigned short* emb = smem + 32768;    // 128 x 64  bf16 = 16 KB, 3-bit swz
  const int tid = threadIdx.x;
  const int w = tid >> 6, lane = tid & 63;
  const int n = lane & 31, h = lane >> 5;
  const unsigned swzA = (unsigned)((n & 31) << 4);  // act key: row&31 (==n for rows n+32k)
  const unsigned swzE = (unsigned)((n & 7) << 4);   // emb key: row&7
  const long pbase = (long)blockIdx.x * 128;

  // ---- embedding: thread t -> point t/2, features (t&1)*32..+31 -----------
  {
    const int pt = tid >> 1, fg = tid & 1;
    const long pg = pbase + pt;
    float c0 = 0.f, c1 = 0.f, c2 = 0.f;
    if (pg < N) {
      const float* pp = pts + pg * 3;
      // nontemporal: pts read once; don't churn weight lines out of L2.
      c0 = __builtin_nontemporal_load(pp);
      c1 = __builtin_nontemporal_load(pp + 1);
      c2 = __builtin_nontemporal_load(pp + 2);
    }
    float x0 = c0 * INV2PI, x1 = c1 * INV2PI, x2 = c2 * INV2PI;
    const unsigned sw = (unsigned)((pt & 7) << 4);
    char* rowp = (char*)emb + (unsigned)(pt * 128);
#pragma unroll
    for (int jb = 0; jb < 2; ++jb) {
      unsigned pk[8];
#pragma unroll
      for (int i = 0; i < 16; i += 2) {
        int f0 = fg * 32 + jb * 16 + i;
        float v0 = embval(f0,     c0, c1, c2, x0, x1, x2);
        float v1 = embval(f0 + 1, c0, c1, c2, x0, x1, x2);
        pk[i >> 1] = cvtpk(v0, v1);
      }
      unsigned base = (unsigned)(fg * 64 + jb * 32);
      *reinterpret_cast<uint4*>(rowp + (base ^ sw)) =
          uint4{pk[0], pk[1], pk[2], pk[3]};
      *reinterpret_cast<uint4*>(rowp + ((base + 16) ^ sw)) =
          uint4{pk[4], pk[5], pk[6], pk[7]};
    }
  }
  __syncthreads();

  do_layer32<4,  128, 0, false>(emb, nullptr, wpk + PK_L0, B.b[0], act, w, n, h, swzE, 0,    swzA);
  do_layer32<16, 512, 0, true >(act, nullptr, wpk + PK_L1, B.b[1], act, w, n, h, swzA, 0,    swzA);
  do_layer32<16, 512, 0, true >(act, nullptr, wpk + PK_L2, B.b[2], act, w, n, h, swzA, 0,    swzA);
  do_layer32<16, 512, 0, true >(act, nullptr, wpk + PK_L3, B.b[3], act, w, n, h, swzA, 0,    swzA);
  do_layer32<16, 512, 0, true >(act, nullptr, wpk + PK_L4, B.b[4], act, w, n, h, swzA, 0,    swzA);
  do_layer32<16, 512, 4, true >(act, emb,     wpk + PK_L5, B.b[5], act, w, n, h, swzA, swzE, swzA);
  do_layer32<16, 512, 0, true >(act, nullptr, wpk + PK_L6, B.b[6], act, w, n, h, swzA, 0,    swzA);
  do_layer32<16, 512, 0, true >(act, nullptr, wpk + PK_L7, B.b[7], act, w, n, h, swzA, 0,    swzA);

  // ---- final 256->4 via 16x16x32: wave w -> pts [32w,32w+32), 2 x 16 ------
  {
    const int l16 = lane & 15, quad = lane >> 4;
    const unsigned short* w8b = wpk + PK_W8 + (unsigned)(l16 * 256 + quad * 8);
    short8 wf[8];
#pragma unroll
    for (int kk = 0; kk < 8; ++kk)
      wf[kk] = *reinterpret_cast<const short8*>(w8b + kk * 32);
    f32x4 bb = *reinterpret_cast<const f32x4*>(b8);
#pragma unroll
    for (int it = 0; it < 2; ++it) {
      const int pt = w * 32 + it * 16 + l16;
      // act key for row pt: (pt&31)<<4 == ((it*16 + l16)&31)<<4
      const unsigned swzF = (unsigned)(((it * 16 + l16) & 31) << 4);
      const char* ba = (const char*)act + (unsigned)(pt * 512);
      f32x4 a4 = {0.f, 0.f, 0.f, 0.f};
#pragma unroll
      for (int kk = 0; kk < 8; ++kk) {
        unsigned off = ((unsigned)(kk * 64 + quad * 16)) ^ swzF;
        short8 b = *reinterpret_cast<const short8*>(ba + off);
        a4 = mfma16(wf[kk], b, a4);
      }
      if (quad == 0) {
        long pg = pbase + pt;
        f32x4 v = a4 + bb;
        if (pg < N)
          __builtin_nontemporal_store(v, reinterpret_cast<f32x4*>(out + pg * 4));
      }
    }
  }
}

// ---------------------------------------------------------------------------
// Fallback (ws too small or dyn-LDS attr refused): round-1 VALU kernel,
// fp32 weights, proven correct.
// ---------------------------------------------------------------------------
__device__ __forceinline__ unsigned pk2s(float a, float b) {
  return (unsigned)f2bf(a) | ((unsigned)f2bf(b) << 16);
}
__device__ __forceinline__ void fb_seg(const unsigned short* src, int kRows,
                                       const float* __restrict__ wr,
                                       int lane, int ps, float acc[4][16]) {
#pragma unroll 4
  for (int k = 0; k < kRows; ++k) {
    const float* p = wr + k * 256 + lane;
    float w0 = p[0], w1 = p[64], w2 = p[128], w3 = p[192];
    const uint4* xr = reinterpret_cast<const uint4*>(src + ((k << 6) + ps));
    uint4 q0 = xr[0], q1 = xr[1];
    float x[16];
    x[0] = bf_lo(q0.x);  x[1] = bf_hi(q0.x);  x[2] = bf_lo(q0.y);  x[3] = bf_hi(q0.y);
    x[4] = bf_lo(q0.z);  x[5] = bf_hi(q0.z);  x[6] = bf_lo(q0.w);  x[7] = bf_hi(q0.w);
    x[8] = bf_lo(q1.x);  x[9] = bf_hi(q1.x);  x[10] = bf_lo(q1.y); x[11] = bf_hi(q1.y);
    x[12] = bf_lo(q1.z); x[13] = bf_hi(q1.z); x[14] = bf_lo(q1.w); x[15] = bf_hi(q1.w);
#pragma unroll
    for (int pp = 0; pp < 16; ++pp) {
      acc[0][pp] = fmaf(w0, x[pp], acc[0][pp]);
      acc[1][pp] = fmaf(w1, x[pp], acc[1][pp]);
      acc[2][pp] = fmaf(w2, x[pp], acc[2][pp]);
      acc[3][pp] = fmaf(w3, x[pp], acc[3][pp]);
    }
  }
}
__device__ __forceinline__ void fb_layer(const unsigned short* srcA, int kA,
                                         const unsigned short* srcB, int kB,
                                         const float* wrA, const float* wrB,
                                         const float* bias,
                                         unsigned short* dst, int lane, int ps) {
  float acc[4][16];
#pragma unroll
  for (int jt = 0; jt < 4; ++jt) {
    float bb = bias[lane + (jt << 6)];
#pragma unroll
    for (int pp = 0; pp < 16; ++pp) acc[jt][pp] = bb;
  }
  fb_seg(srcA, kA, wrA, lane, ps, acc);
  if (srcB) fb_seg(srcB, kB, wrB, lane, ps, acc);
#pragma unroll
  for (int jt = 0; jt < 4; ++jt) {
    unsigned short* dr = dst + (((lane + (jt << 6)) << 6) + ps);
    float r[16];
#pragma unroll
    for (int pp = 0; pp < 16; ++pp) r[pp] = fmaxf(acc[jt][pp], 0.0f);
    uint4 a, b;
    a.x = pk2s(r[0], r[1]);   a.y = pk2s(r[2], r[3]);
    a.z = pk2s(r[4], r[5]);   a.w = pk2s(r[6], r[7]);
    b.x = pk2s(r[8], r[9]);   b.y = pk2s(r[10], r[11]);
    b.z = pk2s(r[12], r[13]); b.w = pk2s(r[14], r[15]);
    reinterpret_cast<uint4*>(dr)[0] = a;
    reinterpret_cast<uint4*>(dr)[1] = b;
  }
}
__launch_bounds__(256, 2)
__global__ void mlp_fallback(const float* __restrict__ pts, int N,
                             WPtrs W, BPtrs B,
                             const float* __restrict__ w8,
                             const float* __restrict__ b8,
                             float* __restrict__ out) {
  __shared__ unsigned short act[256 * 64];
  __shared__ unsigned short emb[64 * 64];
  const int lane = threadIdx.x & 63;
  const int ps = (threadIdx.x >> 6) << 4;
  const long pbase = (long)blockIdx.x * 64 + ps;
#pragma unroll
  for (int i = 0; i < 16; ++i) {
    int idx = (i << 6) + lane;
    int f = idx >> 4, pp = idx & 15;
    float v = 0.0f;
    if (f < 63) {
      float c = (pbase + pp < N) ? pts[(pbase + pp) * 3 + (f / 21)] : 0.0f;
      float x = c * INV2PI;
      v = embval(f, c, c, c, x, x, x);
    }
    emb[(f << 6) + ps + pp] = f2bf(v);
  }
  fb_layer(emb, 63, nullptr, 0, W.w[0], nullptr, B.b[0], act, lane, ps);
#pragma unroll 1
  for (int l = 1; l <= 4; ++l)
    fb_layer(act, 256, nullptr, 0, W.w[l], nullptr, B.b[l], act, lane, ps);
  fb_layer(act, 256, emb, 63, W.w[5], W.w[5] + 256 * 256, B.b[5], act, lane, ps);
#pragma unroll 1
  for (int l = 6; l <= 7; ++l)
    fb_layer(act, 256, nullptr, 0, W.w[l], nullptr, B.b[l], act, lane, ps);
  {
    const int pp = lane & 15, cc = lane >> 4;
    float a = b8[cc];
#pragma unroll 4
    for (int k = 0; k < 256; ++k)
      a = fmaf(bf_lo((unsigned)act[(k << 6) + ps + pp]), w8[(k << 2) + cc], a);
    if (pbase + pp < N) out[(pbase + pp) * 4 + cc] = a;
  }
}

extern "C" void kernel_launch(void* const* d_in, const int* in_sizes, int n_in,
                              void* d_out, int out_size, void* d_ws, size_t ws_size,
                              hipStream_t stream) {
  const float* pts = (const float*)d_in[0];
  WPtrs W; BPtrs B;
  for (int i = 0; i < 8; ++i) {
    W.w[i] = (const float*)d_in[1 + 2 * i];
    B.b[i] = (const float*)d_in[2 + 2 * i];
  }
  const float* w8 = (const float*)d_in[17];
  const float* b8 = (const float*)d_in[18];
  float* out = (float*)d_out;
  const long N = in_sizes[0] / 3;

  const size_t need = (size_t)PK_TOTAL * sizeof(unsigned short);
  if (ws_size >= need) {
    // 80 KB dynamic LDS (act 64K + emb 16K): opt in once. Host-side, not a
    // stream op -> safe under graph capture.
    static hipError_t attr_err = hipFuncSetAttribute(
        reinterpret_cast<const void*>(mlp_mfma),
        hipFuncAttributeMaxDynamicSharedMemorySize, 81920);
    if (attr_err == hipSuccess) {
      unsigned short* wpk = (unsigned short*)d_ws;
      pack_weights<<<1936, 256, 0, stream>>>(W, w8, wpk);
      mlp_mfma<<<(int)((N + 127) / 128), 256, 81920, stream>>>(pts, N, B, b8, wpk, out);
      return;
    }
  }
  mlp_fallback<<<(int)((N + 63) / 64), 256, 0, stream>>>(pts, (int)N, W, B, w8, b8, out);
}